// Round 1
// baseline (69.287 us; speedup 1.0000x reference)
//
#include <hip/hip_runtime.h>
#include <math.h>

// Cox partial-likelihood loss, all-events case.
// loss = (1/N) * sum_j [ log( sum_{i in riskset(j)} exp(pred_i) ) - pred_j ]
// riskset(j) = { i : ytime_i > ytime_j  ||  (ytime_i == ytime_j && i >= j) }
// (tie rule == stable argsort by ytime, matching jnp.argsort default)

#define COX_N 8192
#define JPB 32          // j rows per block
#define SLICES 8        // i-slices per j
#define BLOCK (JPB * SLICES)   // 256 threads
#define IPT (COX_N / SLICES)   // 1024 i's per thread

__global__ __launch_bounds__(BLOCK) void cox_main(const float* __restrict__ pred,
                                                  const float* __restrict__ ytime,
                                                  float* __restrict__ acc) {
    __shared__ float yt_s[COX_N];
    __shared__ float e_s[COX_N];
    __shared__ float partial[SLICES][JPB];
    __shared__ float sp_s[JPB];

    const int tid = threadIdx.x;

    // Stage the whole ytime and exp(pred) arrays into LDS (64 KB), vectorized.
    const float4* p4 = (const float4*)pred;
    const float4* y4 = (const float4*)ytime;
    float4* yts4w = (float4*)yt_s;
    float4* es4w  = (float4*)e_s;
    for (int t = tid; t < COX_N / 4; t += BLOCK) {
        float4 y = y4[t];
        float4 p = p4[t];
        yts4w[t] = y;
        float4 e;
        e.x = __expf(p.x);
        e.y = __expf(p.y);
        e.z = __expf(p.z);
        e.w = __expf(p.w);
        es4w[t] = e;
    }

    const int jl = tid & (JPB - 1);   // 0..31
    const int sl = tid >> 5;          // 0..7  (lanes 0-31 slice s, 32-63 slice s+1)
    const int j  = blockIdx.x * JPB + jl;

    const float ytj = ytime[j];
    if (sl == 0) sp_s[jl] = pred[j];

    __syncthreads();

    // Accumulate riskset sum over this thread's i-slice.
    float r = 0.0f;
    const int base = sl * IPT;
    const float4* yts4 = (const float4*)(yt_s + base);
    const float4* es4  = (const float4*)(e_s + base);
#pragma unroll 4
    for (int t = 0; t < IPT / 4; ++t) {
        float4 y = yts4[t];
        float4 e = es4[t];
        int i0 = base + t * 4;
        r += ((y.x > ytj) || ((y.x == ytj) && (i0 + 0 >= j))) ? e.x : 0.0f;
        r += ((y.y > ytj) || ((y.y == ytj) && (i0 + 1 >= j))) ? e.y : 0.0f;
        r += ((y.z > ytj) || ((y.z == ytj) && (i0 + 2 >= j))) ? e.z : 0.0f;
        r += ((y.w > ytj) || ((y.w == ytj) && (i0 + 3 >= j))) ? e.w : 0.0f;
    }
    partial[sl][jl] = r;
    __syncthreads();

    // Lanes 0..31 (wave 0): combine the 8 slice partials for each j,
    // take log, subtract sp_j, reduce across the 32 j's, one atomic/block.
    if (tid < JPB) {
        float rt = 0.0f;
#pragma unroll
        for (int s = 0; s < SLICES; ++s) rt += partial[s][tid];
        float loss = logf(rt) - sp_s[tid];
#pragma unroll
        for (int off = 16; off > 0; off >>= 1) loss += __shfl_down(loss, off);
        if (tid == 0) atomicAdd(acc, loss);
    }
}

__global__ void cox_fin(const float* __restrict__ acc, float* __restrict__ out) {
    out[0] = acc[0] * (1.0f / (float)COX_N);
}

extern "C" void kernel_launch(void* const* d_in, const int* in_sizes, int n_in,
                              void* d_out, int out_size, void* d_ws, size_t ws_size,
                              hipStream_t stream) {
    const float* pred  = (const float*)d_in[0];
    const float* ytime = (const float*)d_in[1];
    float* acc = (float*)d_ws;
    float* out = (float*)d_out;

    hipMemsetAsync(acc, 0, sizeof(float), stream);
    cox_main<<<COX_N / JPB, BLOCK, 0, stream>>>(pred, ytime, acc);
    cox_fin<<<1, 1, 0, stream>>>(acc, out);
}

// Round 2
// 15.593 us; speedup vs baseline: 4.4433x; 4.4433x over previous
//
#include <hip/hip_runtime.h>
#include <math.h>

// Cox partial-likelihood loss, all-events case.
// loss = (1/N) * sum_j [ log( sum_{i in riskset(j)} exp(pred_i) ) - pred_j ]
// riskset(j) = { i : (yt_i, i) >= (yt_j, j) lexicographically }  (stable argsort rule)
// Encoded as one u64 compare: key = (float_bits(yt) << 13) | index
// (yt in [0,1) => nonnegative floats => bit pattern is order-preserving).

#define COX_N 8192
#define BLOCK 256
#define JPB 64                 // j's per block
#define CI 1024                // i-chunk elements per block
#define GJ (COX_N / JPB)       // 128
#define GI (COX_N / CI)        // 8
#define JPT 4                  // j's per thread
#define JGRP (JPB / JPT)       // 16 j-groups
#define ISL (BLOCK / JGRP)     // 16 i-slices
#define IPT (CI / ISL)         // 64 i's per thread

typedef __attribute__((ext_vector_type(2))) unsigned long long ull2;

__global__ __launch_bounds__(BLOCK) void cox_main(const float* __restrict__ pred,
                                                  const float* __restrict__ ytime,
                                                  float* __restrict__ partial) {
    __shared__ unsigned long long key_s[CI];  // 8 KB
    __shared__ float e_s[CI];                 // 4 KB
    __shared__ float red[JPB][ISL + 1];       // padded: no bank conflict

    const int tid = threadIdx.x;
    const int bj = blockIdx.x;      // j-group index
    const int bi = blockIdx.y;      // i-chunk index
    const int ibase = bi * CI;

    // ---- stage this block's i-chunk: key + exp(pred) ----
    {
        const float4* y4 = (const float4*)(ytime + ibase);
        const float4* p4 = (const float4*)(pred + ibase);
        float4 y = y4[tid];
        float4 p = p4[tid];
        int gi = ibase + tid * 4;
        key_s[tid * 4 + 0] = ((unsigned long long)__float_as_uint(y.x) << 13) | (unsigned)(gi + 0);
        key_s[tid * 4 + 1] = ((unsigned long long)__float_as_uint(y.y) << 13) | (unsigned)(gi + 1);
        key_s[tid * 4 + 2] = ((unsigned long long)__float_as_uint(y.z) << 13) | (unsigned)(gi + 2);
        key_s[tid * 4 + 3] = ((unsigned long long)__float_as_uint(y.w) << 13) | (unsigned)(gi + 3);
        e_s[tid * 4 + 0] = __expf(p.x);
        e_s[tid * 4 + 1] = __expf(p.y);
        e_s[tid * 4 + 2] = __expf(p.z);
        e_s[tid * 4 + 3] = __expf(p.w);
    }

    const int jg = tid & (JGRP - 1);   // 0..15: which j-group
    const int is = tid >> 4;           // 0..15: which i-slice (wave-uniform per 16 lanes -> LDS broadcast)
    const int j0 = bj * JPB + jg * JPT;

    unsigned long long jkey[JPT];
    float r[JPT];
#pragma unroll
    for (int q = 0; q < JPT; ++q) {
        int j = j0 + q;
        jkey[q] = ((unsigned long long)__float_as_uint(ytime[j]) << 13) | (unsigned)j;
        r[q] = 0.0f;
    }

    __syncthreads();

    // ---- inner loop: this thread's 64-element i-slice vs its 4 j's ----
    const ull2* k2 = (const ull2*)(key_s + is * IPT);
    const float2* e2 = (const float2*)(e_s + is * IPT);
#pragma unroll 8
    for (int t = 0; t < IPT / 2; ++t) {
        ull2 k = k2[t];
        float2 e = e2[t];
#pragma unroll
        for (int q = 0; q < JPT; ++q) {
            r[q] += (k.x >= jkey[q]) ? e.x : 0.0f;
            r[q] += (k.y >= jkey[q]) ? e.y : 0.0f;
        }
    }

    // ---- reduce the 16 i-slices per j ----
#pragma unroll
    for (int q = 0; q < JPT; ++q) red[jg * JPT + q][is] = r[q];
    __syncthreads();

    if (tid < JPB) {
        float s = 0.0f;
#pragma unroll
        for (int t = 0; t < ISL; ++t) s += red[tid][t];
        partial[bi * COX_N + bj * JPB + tid] = s;   // disjoint slots, no atomics
    }
}

__global__ __launch_bounds__(256) void cox_fin(const float* __restrict__ partial,
                                               const float* __restrict__ pred,
                                               float* __restrict__ bsum) {
    const int tid = threadIdx.x;
    const int j = blockIdx.x * 256 + tid;
    float rsum = 0.0f;
#pragma unroll
    for (int c = 0; c < GI; ++c) rsum += partial[c * COX_N + j];
    float loss = logf(rsum) - pred[j];
#pragma unroll
    for (int off = 32; off > 0; off >>= 1) loss += __shfl_down(loss, off);
    __shared__ float wsum[4];
    if ((tid & 63) == 0) wsum[tid >> 6] = loss;
    __syncthreads();
    if (tid == 0) bsum[blockIdx.x] = wsum[0] + wsum[1] + wsum[2] + wsum[3];
}

__global__ void cox_fin2(const float* __restrict__ bsum, float* __restrict__ out) {
    const int tid = threadIdx.x;
    float v = (tid < 32) ? bsum[tid] : 0.0f;
#pragma unroll
    for (int off = 32; off > 0; off >>= 1) v += __shfl_down(v, off);
    if (tid == 0) out[0] = v * (1.0f / (float)COX_N);
}

extern "C" void kernel_launch(void* const* d_in, const int* in_sizes, int n_in,
                              void* d_out, int out_size, void* d_ws, size_t ws_size,
                              hipStream_t stream) {
    const float* pred  = (const float*)d_in[0];
    const float* ytime = (const float*)d_in[1];
    float* partial = (float*)d_ws;                       // GI * N floats = 256 KB
    float* bsum    = (float*)d_ws + GI * COX_N;          // 32 floats
    float* out     = (float*)d_out;

    cox_main<<<dim3(GJ, GI), BLOCK, 0, stream>>>(pred, ytime, partial);
    cox_fin<<<COX_N / 256, 256, 0, stream>>>(partial, pred, bsum);
    cox_fin2<<<1, 64, 0, stream>>>(bsum, out);
}